// Round 15
// baseline (186.251 us; speedup 1.0000x reference)
//
#include <hip/hip_runtime.h>
#include <hip/hip_fp16.h>
#include <math.h>

#define NODES 100000
#define NEDGE 1600000
#define ETOT  (NEDGE + NODES)
#define FIN   128
#define C1    64
#define NEG   0.2f
#define BNEPS 1e-5f
#define BNBLK 128
#define PSCALE 0.00390625f   // 2^-8 : fp16 accumulation scale in agg1

#define BK     128                         // nodes per bucket
#define NBUCK  ((NODES + BK - 1) / BK)     // 782
#define PCAP   2816                        // per-bucket edge cap (mean 2048, +17 sigma)
#define PTILE  4096                        // edges per k_part block
#define GB1    ((NODES + 63) / 64)         // gemm1 blocks: 1563
#define PB     ((NEDGE + PTILE - 1) / PTILE)  // part blocks: 391

typedef __attribute__((ext_vector_type(8))) short bf16x8;
typedef __attribute__((ext_vector_type(4))) float f32x4;

static __device__ __forceinline__ short f2bf(float f) {
    unsigned u = __builtin_bit_cast(unsigned, f);
    unsigned r = (u + 0x7FFFu + ((u >> 16) & 1u)) >> 16;
    return (short)r;
}

// ---------------- prep: wad vectors + W1s bf16 B-fragments + bcur zero ----------------

__global__ __launch_bounds__(256) void k_prep(const float* __restrict__ W1s,
                                              const float* __restrict__ W1d, const float* __restrict__ a1d,
                                              const float* __restrict__ W2d, const float* __restrict__ a2d,
                                              float* wad1, float* wad2, unsigned short* __restrict__ wfrag,
                                              int* __restrict__ bcur) {
    int t = threadIdx.x;
    int b = blockIdx.x;
    if (b == 33) {
        for (int i = t; i < NBUCK; i += 256) bcur[i] = 0;
    } else if (b == 32) {
        if (t < FIN) {
            float acc = 0.f;
            for (int c = 0; c < C1; c++) acc = fmaf(W1d[t * C1 + c], a1d[c], acc);
            wad1[t] = acc;
        }
        if (t < C1) {
            wad2[t] = fmaf(W2d[t * 2], a2d[0], W2d[t * 2 + 1] * a2d[1]);
        }
    } else {
        int idx = b * 256 + t;          // 0..8191
        int j  = idx & 7;
        int ln = (idx >> 3) & 63;
        int it = (idx >> 9) & 3;
        int ct = idx >> 11;
        int k  = it * 32 + (ln >> 4) * 8 + j;
        int ch = ct * 16 + (ln & 15);
        wfrag[idx] = (unsigned short)f2bf(W1s[k * C1 + ch]);
    }
}

// ---------------- fused: gemm1 (blocks 0..GB1) + edge partition (blocks GB1..GB1+PB) ----
// Independent work overlapped in one launch: gemm1 is compute/latency-bound,
// part is memory-bound; stream-serial launches cannot overlap them.

__device__ __forceinline__ void gemm1_body(int blk, const float* __restrict__ x,
                                           const unsigned short* __restrict__ wfrag,
                                           const float* __restrict__ wad, const float* __restrict__ a_src,
                                           __half* __restrict__ hsh, float* __restrict__ as_out,
                                           float* __restrict__ ad_out) {
    int t = threadIdx.x;
    int lane = t & 63;
    int wv = t >> 6;
    int n0 = blk * 64 + wv * 16;
    int li = lane & 15, g = lane >> 4;

    int row = n0 + li;
    bool rv = row < NODES;
    const float* xr = x + (size_t)row * FIN + g * 8;

    f32x4 acc0 = {0.f,0.f,0.f,0.f}, acc1 = {0.f,0.f,0.f,0.f};
    f32x4 acc2 = {0.f,0.f,0.f,0.f}, acc3 = {0.f,0.f,0.f,0.f};
    bf16x8 af[4];
    float adp = 0.f;

    #pragma unroll
    for (int it = 0; it < 4; it++) {
        float xv[8];
        if (rv) {
            float4 lo = *reinterpret_cast<const float4*>(xr + it * 32);
            float4 hi = *reinterpret_cast<const float4*>(xr + it * 32 + 4);
            xv[0]=lo.x; xv[1]=lo.y; xv[2]=lo.z; xv[3]=lo.w;
            xv[4]=hi.x; xv[5]=hi.y; xv[6]=hi.z; xv[7]=hi.w;
        } else {
            #pragma unroll
            for (int j = 0; j < 8; j++) xv[j] = 0.f;
        }
        const float* wr = wad + g * 8 + it * 32;
        float4 wlo = *reinterpret_cast<const float4*>(wr);
        float4 whi = *reinterpret_cast<const float4*>(wr + 4);
        adp = fmaf(xv[0], wlo.x, adp); adp = fmaf(xv[1], wlo.y, adp);
        adp = fmaf(xv[2], wlo.z, adp); adp = fmaf(xv[3], wlo.w, adp);
        adp = fmaf(xv[4], whi.x, adp); adp = fmaf(xv[5], whi.y, adp);
        adp = fmaf(xv[6], whi.z, adp); adp = fmaf(xv[7], whi.w, adp);
        bf16x8 a;
        #pragma unroll
        for (int j = 0; j < 8; j++) a[j] = f2bf(xv[j]);
        af[it] = a;
    }

    const bf16x8* wfv = reinterpret_cast<const bf16x8*>(wfrag);
    #pragma unroll
    for (int it = 0; it < 4; it++) {
        acc0 = __builtin_amdgcn_mfma_f32_16x16x32_bf16(af[it], wfv[(0*4+it)*64 + lane], acc0, 0, 0, 0);
        acc1 = __builtin_amdgcn_mfma_f32_16x16x32_bf16(af[it], wfv[(1*4+it)*64 + lane], acc1, 0, 0, 0);
        acc2 = __builtin_amdgcn_mfma_f32_16x16x32_bf16(af[it], wfv[(2*4+it)*64 + lane], acc2, 0, 0, 0);
        acc3 = __builtin_amdgcn_mfma_f32_16x16x32_bf16(af[it], wfv[(3*4+it)*64 + lane], acc3, 0, 0, 0);
    }

    adp += __shfl_xor(adp, 16);
    adp += __shfl_xor(adp, 32);
    if (lane < 16 && rv) ad_out[row] = adp;

    float a0 = a_src[0 * 16 + li], a1 = a_src[1 * 16 + li];
    float a2 = a_src[2 * 16 + li], a3 = a_src[3 * 16 + li];
    float asp0 = acc0[0]*a0 + acc1[0]*a1 + acc2[0]*a2 + acc3[0]*a3;
    float asp1 = acc0[1]*a0 + acc1[1]*a1 + acc2[1]*a2 + acc3[1]*a3;
    float asp2 = acc0[2]*a0 + acc1[2]*a1 + acc2[2]*a2 + acc3[2]*a3;
    float asp3 = acc0[3]*a0 + acc1[3]*a1 + acc2[3]*a2 + acc3[3]*a3;
    #pragma unroll
    for (int o = 1; o <= 8; o <<= 1) {
        asp0 += __shfl_xor(asp0, o);
        asp1 += __shfl_xor(asp1, o);
        asp2 += __shfl_xor(asp2, o);
        asp3 += __shfl_xor(asp3, o);
    }
    if ((lane & 12) == 0) {
        int r = lane & 3;
        int n = n0 + 4 * g + r;
        if (n < NODES) {
            float av = (r == 0) ? asp0 : (r == 1) ? asp1 : (r == 2) ? asp2 : asp3;
            as_out[n] = av;
        }
    }

    #pragma unroll
    for (int r = 0; r < 4; r++) {
        int n = n0 + 4 * g + r;
        if (n < NODES) {
            __half* hb = hsh + (size_t)n * C1 + li;
            hb[ 0] = __float2half(acc0[r]);
            hb[16] = __float2half(acc1[r]);
            hb[32] = __float2half(acc2[r]);
            hb[48] = __float2half(acc3[r]);
        }
    }
}

__global__ __launch_bounds__(256) void k_fused1(const float* __restrict__ x,
                                                const unsigned short* __restrict__ wfrag,
                                                const float* __restrict__ wad, const float* __restrict__ a_src,
                                                __half* __restrict__ hsh, float* __restrict__ as_out,
                                                float* __restrict__ ad_out,
                                                const int* __restrict__ ei, int* bcur,
                                                unsigned* __restrict__ tmp) {
    __shared__ int hist[NBUCK], hbase[NBUCK];
    if (blockIdx.x < GB1) {
        gemm1_body(blockIdx.x, x, wfrag, wad, a_src, hsh, as_out, ad_out);
        return;
    }
    // ---- partition body ----
    int t = threadIdx.x;
    for (int i = t; i < NBUCK; i += 256) hist[i] = 0;
    __syncthreads();
    const int* srcs = ei;
    const int* dsts = ei + NEDGE;
    int e_base = (blockIdx.x - GB1) * PTILE;
    unsigned pack[16];
    int bkt[16], slot[16];
    #pragma unroll
    for (int i = 0; i < 16; i++) {
        int e = e_base + i * 256 + t;
        bool valid = e < NEDGE;
        int s = valid ? srcs[e] : 0;
        int d = valid ? dsts[e] : 0;
        if ((unsigned)d >= NODES || (unsigned)s >= NODES) valid = false;
        bkt[i] = valid ? (d >> 7) : -1;
        pack[i] = (unsigned)s | ((unsigned)(d & (BK - 1)) << 17);
        slot[i] = valid ? atomicAdd(&hist[bkt[i]], 1) : -1;
    }
    __syncthreads();
    for (int i = t; i < NBUCK; i += 256)
        hbase[i] = hist[i] ? atomicAdd(&bcur[i], hist[i]) : 0;
    __syncthreads();
    #pragma unroll
    for (int i = 0; i < 16; i++) {
        if (slot[i] >= 0) {
            int pos = hbase[bkt[i]] + slot[i];
            if (pos < PCAP) tmp[(size_t)bkt[i] * PCAP + pos] = pack[i];
        }
    }
}

// P2: per bucket: own prefix-base -> counts -> local scan (offs) -> LDS scatter ->
// coalesced csr+pe write. p = exp(lrelu(as1[s]+ad1[d])) computed inline at writeout.
__global__ __launch_bounds__(256) void k_build(const unsigned* __restrict__ tmp, const int* __restrict__ bcur,
                                               const float* __restrict__ as1, const float* __restrict__ ad1,
                                               int* __restrict__ offs, int* __restrict__ csr,
                                               uint2* __restrict__ pe) {
    __shared__ int cnt[BK];
    __shared__ int ps_[BK];
    __shared__ int red[256];
    __shared__ int stage[PCAP + BK];
    int t = threadIdx.x;
    int b = blockIdx.x;
    int ecnt = bcur[b]; if (ecnt > PCAP) ecnt = PCAP;

    int part = 0;
    for (int i = t; i < b; i += 256) part += bcur[i];
    red[t] = part;
    __syncthreads();
    for (int o = 128; o; o >>= 1) {
        if (t < o) red[t] += red[t + o];
        __syncthreads();
    }
    int csrbase = red[0] + BK * b;
    const unsigned* ebuf = tmp + (size_t)b * PCAP;

    if (t < BK) cnt[t] = 0;
    __syncthreads();
    for (int e = t; e < ecnt; e += 256) {
        int dl = (ebuf[e] >> 17) & (BK - 1);
        atomicAdd(&cnt[dl], 1);
    }
    __syncthreads();
    int gn = b * BK + t;
    int own = 0;
    if (t < BK) {
        own = cnt[t] + ((gn < NODES) ? 1 : 0);
        ps_[t] = own;
    }
    __syncthreads();
    for (int o = 1; o < BK; o <<= 1) {
        int add = (t < BK && t >= o) ? ps_[t - o] : 0;
        __syncthreads();
        if (t < BK) ps_[t] += add;
        __syncthreads();
    }
    int total = ps_[BK - 1];
    if (t < BK && gn < NODES) {
        int excl = ps_[t] - own;
        stage[excl] = gn | (t << 17);
        cnt[t] = excl + 1;
        offs[gn] = csrbase + excl;
    }
    if (b == NBUCK - 1 && t == 0) offs[NODES] = ETOT;
    if (b == NBUCK - 1 && t < 16) pe[ETOT + t] = make_uint2(0u, 0u);
    __syncthreads();
    for (int e = t; e < ecnt; e += 256) {
        unsigned p = ebuf[e];
        int dl = (p >> 17) & (BK - 1);
        int slot = atomicAdd(&cnt[dl], 1);
        stage[slot] = (int)p;
    }
    __syncthreads();
    for (int j = t; j < total; j += 256) {
        int v = stage[j];
        int s = v & 0x1FFFF;
        int d = b * BK + (int)(((unsigned)v) >> 17);
        csr[csrbase + j] = s;
        float e = as1[s] + ad1[d];
        e = e > 0.f ? e : NEG * e;
        float p = __expf(fminf(e, 60.f));
        pe[csrbase + j] = make_uint2((unsigned)s, __float_as_uint(p));
    }
}

// ---------------- aggregation layer 1: pure gather, packed-fp16 accumulate ----------------

__global__ __launch_bounds__(256) void k_agg1(const int* __restrict__ offs, const uint2* __restrict__ pe,
                                              const __half* __restrict__ hsh, const float* __restrict__ b1,
                                              __half* __restrict__ h1h) {
    int w = threadIdx.x >> 6, lane = threadIdx.x & 63;
    int node = blockIdx.x * 4 + w;
    if (node >= NODES) return;
    int e0 = offs[node], e1 = offs[node + 1];
    int g = lane >> 4, l = lane & 15;
    __half2 acc01 = __floats2half2_rn(0.f, 0.f);
    __half2 acc23 = __floats2half2_rn(0.f, 0.f);
    float ssum = 0.f;
    for (int base = e0; base < e1; base += 16) {
        int ea = base + g, eb = ea + 4, ec = ea + 8, ed = ea + 12;
        uint2 spa = pe[ea];
        uint2 spb = pe[eb];
        uint2 spc = pe[ec];
        uint2 spd = pe[ed];
        float pa = ea < e1 ? __uint_as_float(spa.y) : 0.f;
        float pb = eb < e1 ? __uint_as_float(spb.y) : 0.f;
        float pc = ec < e1 ? __uint_as_float(spc.y) : 0.f;
        float pd = ed < e1 ? __uint_as_float(spd.y) : 0.f;
        uint2 ra = *reinterpret_cast<const uint2*>(hsh + (size_t)spa.x * C1 + l * 4);
        uint2 rb = *reinterpret_cast<const uint2*>(hsh + (size_t)spb.x * C1 + l * 4);
        uint2 rc = *reinterpret_cast<const uint2*>(hsh + (size_t)spc.x * C1 + l * 4);
        uint2 rd = *reinterpret_cast<const uint2*>(hsh + (size_t)spd.x * C1 + l * 4);
        ssum += (pa + pb) + (pc + pd);
        __half2 pha = __float2half2_rn(pa * PSCALE);
        __half2 phb = __float2half2_rn(pb * PSCALE);
        __half2 phc = __float2half2_rn(pc * PSCALE);
        __half2 phd = __float2half2_rn(pd * PSCALE);
        acc01 = __hfma2(pha, *reinterpret_cast<const __half2*>(&ra.x), acc01);
        acc23 = __hfma2(pha, *reinterpret_cast<const __half2*>(&ra.y), acc23);
        acc01 = __hfma2(phb, *reinterpret_cast<const __half2*>(&rb.x), acc01);
        acc23 = __hfma2(phb, *reinterpret_cast<const __half2*>(&rb.y), acc23);
        acc01 = __hfma2(phc, *reinterpret_cast<const __half2*>(&rc.x), acc01);
        acc23 = __hfma2(phc, *reinterpret_cast<const __half2*>(&rc.y), acc23);
        acc01 = __hfma2(phd, *reinterpret_cast<const __half2*>(&rd.x), acc01);
        acc23 = __hfma2(phd, *reinterpret_cast<const __half2*>(&rd.y), acc23);
    }
    ssum += __shfl_xor(ssum, 16); ssum += __shfl_xor(ssum, 32);
    unsigned u01 = *reinterpret_cast<unsigned*>(&acc01);
    unsigned u23 = *reinterpret_cast<unsigned*>(&acc23);
    unsigned v01 = (unsigned)__shfl_xor((int)u01, 16);
    unsigned v23 = (unsigned)__shfl_xor((int)u23, 16);
    acc01 = __hadd2(acc01, *reinterpret_cast<__half2*>(&v01));
    acc23 = __hadd2(acc23, *reinterpret_cast<__half2*>(&v23));
    u01 = *reinterpret_cast<unsigned*>(&acc01);
    u23 = *reinterpret_cast<unsigned*>(&acc23);
    v01 = (unsigned)__shfl_xor((int)u01, 32);
    v23 = (unsigned)__shfl_xor((int)u23, 32);
    acc01 = __hadd2(acc01, *reinterpret_cast<__half2*>(&v01));
    acc23 = __hadd2(acc23, *reinterpret_cast<__half2*>(&v23));
    if (g == 0) {
        float inv = 256.0f / (ssum + 1e-16f);
        float2 f01 = __half22float2(acc01);
        float2 f23 = __half22float2(acc23);
        float4 bv = reinterpret_cast<const float4*>(b1)[l];
        __half2 r01 = __floats2half2_rn(fmaf(f01.x, inv, bv.x), fmaf(f01.y, inv, bv.y));
        __half2 r23 = __floats2half2_rn(fmaf(f23.x, inv, bv.z), fmaf(f23.y, inv, bv.w));
        uint2 packed = make_uint2(*reinterpret_cast<unsigned*>(&r01), *reinterpret_cast<unsigned*>(&r23));
        reinterpret_cast<uint2*>(h1h + (size_t)node * C1)[l] = packed;
    }
}

// ---------------- BN stats: deterministic per-block partials (fp16 input) ----------------

__global__ __launch_bounds__(256) void k_bnstats(const __half* __restrict__ h1h, float* __restrict__ bnpart) {
    __shared__ float ls[256], lq[256];
    int t = threadIdx.x;
    int c = t & 63, g = t >> 6;
    float s = 0.f, q = 0.f;
    for (int n = blockIdx.x * 4 + g; n < NODES; n += BNBLK * 4) {
        float v = __half2float(h1h[(size_t)n * C1 + c]);
        s += v;
        q = fmaf(v, v, q);
    }
    ls[t] = s; lq[t] = q;
    __syncthreads();
    if (t < 64) {
        bnpart[(size_t)blockIdx.x * 128 + t]      = ls[t] + ls[t + 64] + ls[t + 128] + ls[t + 192];
        bnpart[(size_t)blockIdx.x * 128 + 64 + t] = lq[t] + lq[t + 64] + lq[t + 128] + lq[t + 192];
    }
}

// ---------------- BN finalize (inline) + apply + ReLU + GEMM2 (+alpha dots) ----------------

__global__ __launch_bounds__(256) void k_bngemm2(const __half* __restrict__ h1h, const float* __restrict__ bnpart,
                                                 const float* __restrict__ gamma, const float* __restrict__ beta,
                                                 const float* __restrict__ W2s,
                                                 const float* __restrict__ wad2, const float* __restrict__ a2s,
                                                 float* __restrict__ hs2, float* __restrict__ as2,
                                                 float* __restrict__ ad2) {
    __shared__ float sc_s[64], sh_s[64];
    int t = threadIdx.x;
    if (t < 64) {
        float s = 0.f, q = 0.f;
        for (int b = 0; b < BNBLK; b++) {
            s += bnpart[(size_t)b * 128 + t];
            q += bnpart[(size_t)b * 128 + 64 + t];
        }
        float mu = s * (1.0f / NODES);
        float var = q * (1.0f / NODES) - mu * mu;
        if (var < 0.f) var = 0.f;
        float rinv = 1.0f / sqrtf(var + BNEPS);
        float sc = gamma[t] * rinv;
        sc_s[t] = sc;
        sh_s[t] = beta[t] - mu * sc;
    }
    __syncthreads();
    int n = blockIdx.x * 256 + t;
    if (n >= NODES) return;
    const uint2* hr = reinterpret_cast<const uint2*>(h1h + (size_t)n * C1);
    float h0 = 0.f, h1v = 0.f, adv = 0.f;
    #pragma unroll
    for (int c4 = 0; c4 < 16; c4++) {
        uint2 u = hr[c4];
        float2 v01 = __half22float2(*reinterpret_cast<const __half2*>(&u.x));
        float2 v23 = __half22float2(*reinterpret_cast<const __half2*>(&u.y));
        float vv[4] = {v01.x, v01.y, v23.x, v23.y};
        #pragma unroll
        for (int j = 0; j < 4; j++) {
            int c = c4 * 4 + j;
            float y = fmaf(vv[j], sc_s[c], sh_s[c]);
            y = fmaxf(y, 0.f);
            h0 = fmaf(y, W2s[c * 2 + 0], h0);
            h1v = fmaf(y, W2s[c * 2 + 1], h1v);
            adv = fmaf(y, wad2[c], adv);
        }
    }
    hs2[n * 2 + 0] = h0;
    hs2[n * 2 + 1] = h1v;
    as2[n] = fmaf(h0, a2s[0], h1v * a2s[1]);
    ad2[n] = adv;
}

// ---------------- aggregation layer 2: 16 lanes per node (mean degree ~17) ----------------

__global__ __launch_bounds__(256) void k_agg2(const int* __restrict__ offs, const int* __restrict__ csr,
                                              const float* __restrict__ as2, const float* __restrict__ ad2,
                                              const float* __restrict__ hs2, const float* __restrict__ b2,
                                              float* __restrict__ out) {
    int sub = threadIdx.x >> 4, l = threadIdx.x & 15;
    int node = blockIdx.x * 16 + sub;
    if (node >= NODES) return;
    int e0 = offs[node], e1 = offs[node + 1];
    float adn = ad2[node];
    float ssum = 0.f, A0 = 0.f, A1 = 0.f;
    const float2* h2 = reinterpret_cast<const float2*>(hs2);
    for (int e = e0 + l; e < e1; e += 16) {
        int s = csr[e];
        float v = as2[s] + adn;
        v = v > 0.f ? v : NEG * v;
        float p = __expf(fminf(v, 60.f));
        ssum += p;
        float2 hv = h2[s];
        A0 = fmaf(p, hv.x, A0);
        A1 = fmaf(p, hv.y, A1);
    }
    #pragma unroll
    for (int o = 1; o < 16; o <<= 1) {
        ssum += __shfl_xor(ssum, o);
        A0   += __shfl_xor(A0, o);
        A1   += __shfl_xor(A1, o);
    }
    if (l == 0) {
        float inv = 1.0f / (ssum + 1e-16f);
        float2 r = make_float2(fmaf(A0, inv, b2[0]), fmaf(A1, inv, b2[1]));
        reinterpret_cast<float2*>(out)[node] = r;
    }
}

// ---------------- host ----------------

static inline size_t align256(size_t x) { return (x + 255) & ~size_t(255); }

extern "C" void kernel_launch(void* const* d_in, const int* in_sizes, int n_in,
                              void* d_out, int out_size, void* d_ws, size_t ws_size,
                              hipStream_t stream) {
    const float* x     = (const float*)d_in[0];
    const int*   ei    = (const int*)d_in[1];
    const float* W1s   = (const float*)d_in[2];
    const float* W1d   = (const float*)d_in[3];
    const float* a1s   = (const float*)d_in[4];
    const float* a1d   = (const float*)d_in[5];
    const float* b1    = (const float*)d_in[6];
    const float* gamma = (const float*)d_in[7];
    const float* beta  = (const float*)d_in[8];
    const float* W2s   = (const float*)d_in[9];
    const float* W2d   = (const float*)d_in[10];
    const float* a2s   = (const float*)d_in[11];
    const float* a2d   = (const float*)d_in[12];
    const float* b2    = (const float*)d_in[13];
    float* out = (float*)d_out;

    char* w = (char*)d_ws;
    size_t off = 0;
    auto alloc = [&](size_t bytes) -> void* {
        void* p = w + off;
        off = align256(off + bytes);
        return p;
    };
    int* offs     = (int*)alloc((size_t)(NODES + 1) * 4);
    int* bcur     = (int*)alloc((size_t)NBUCK * 4);
    int* csr      = (int*)alloc((size_t)ETOT * 4);
    uint2* pe     = (uint2*)alloc((size_t)(ETOT + 16) * 8);
    __half* hs1h  = (__half*)alloc((size_t)NODES * C1 * 2);
    float* as1    = (float*)alloc((size_t)NODES * 4);
    float* ad1    = (float*)alloc((size_t)NODES * 4);
    __half* h1h   = (__half*)alloc((size_t)NODES * C1 * 2);
    float* csrtmp_own = (float*)alloc((size_t)NBUCK * PCAP * 4);
    float* hs2    = (float*)alloc((size_t)NODES * 2 * 4);
    float* as2    = (float*)alloc((size_t)NODES * 4);
    float* ad2    = (float*)alloc((size_t)NODES * 4);
    float* wad1   = (float*)alloc(FIN * 4);
    float* wad2   = (float*)alloc(C1 * 4);
    unsigned short* wfrag = (unsigned short*)alloc(8192 * 2);
    float* bnpart = (float*)alloc((size_t)BNBLK * 128 * 4);
    if (off > ws_size) return;

    unsigned* csr_tmp = (unsigned*)csrtmp_own;

    k_prep<<<34, 256, 0, stream>>>(W1s, W1d, a1d, W2d, a2d, wad1, wad2, wfrag, bcur);
    k_fused1<<<GB1 + PB, 256, 0, stream>>>(x, wfrag, wad1, a1s, hs1h, as1, ad1, ei, bcur, csr_tmp);
    k_build<<<NBUCK, 256, 0, stream>>>(csr_tmp, bcur, as1, ad1, offs, csr, pe);
    k_agg1<<<(NODES + 3) / 4, 256, 0, stream>>>(offs, pe, hs1h, b1, h1h);
    k_bnstats<<<BNBLK, 256, 0, stream>>>(h1h, bnpart);
    k_bngemm2<<<(NODES + 255) / 256, 256, 0, stream>>>(h1h, bnpart, gamma, beta, W2s, wad2, a2s, hs2, as2, ad2);
    k_agg2<<<(NODES + 15) / 16, 256, 0, stream>>>(offs, csr, as2, ad2, hs2, b2, out);
}

// Round 16
// 144.065 us; speedup vs baseline: 1.2928x; 1.2928x over previous
//
#include <hip/hip_runtime.h>
#include <hip/hip_fp16.h>
#include <math.h>

#define NODES 100000
#define NEDGE 1600000
#define ETOT  (NEDGE + NODES)
#define FIN   128
#define C1    64
#define NEG   0.2f
#define BNEPS 1e-5f
#define BNBLK 512
#define PSCALE 0.00390625f   // 2^-8 : fp16 accumulation scale in agg1

#define BK     128                         // nodes per bucket
#define NBUCK  ((NODES + BK - 1) / BK)     // 782
#define PCAP   2816                        // per-bucket edge cap (mean 2048, +17 sigma)
#define PTILE  4096                        // edges per k_part block
#define GB1    ((NODES + 63) / 64)         // gemm1 blocks: 1563
#define PB     ((NEDGE + PTILE - 1) / PTILE)  // part blocks: 391

typedef __attribute__((ext_vector_type(8))) short bf16x8;
typedef __attribute__((ext_vector_type(4))) float f32x4;

static __device__ __forceinline__ short f2bf(float f) {
    unsigned u = __builtin_bit_cast(unsigned, f);
    unsigned r = (u + 0x7FFFu + ((u >> 16) & 1u)) >> 16;
    return (short)r;
}

// ---------------- prep: wad vectors + W1s bf16 B-fragments + bcur zero ----------------

__global__ __launch_bounds__(256) void k_prep(const float* __restrict__ W1s,
                                              const float* __restrict__ W1d, const float* __restrict__ a1d,
                                              const float* __restrict__ W2d, const float* __restrict__ a2d,
                                              float* wad1, float* wad2, unsigned short* __restrict__ wfrag,
                                              int* __restrict__ bcur) {
    int t = threadIdx.x;
    int b = blockIdx.x;
    if (b == 33) {
        for (int i = t; i < NBUCK; i += 256) bcur[i] = 0;
    } else if (b == 32) {
        if (t < FIN) {
            float acc = 0.f;
            for (int c = 0; c < C1; c++) acc = fmaf(W1d[t * C1 + c], a1d[c], acc);
            wad1[t] = acc;
        }
        if (t < C1) {
            wad2[t] = fmaf(W2d[t * 2], a2d[0], W2d[t * 2 + 1] * a2d[1]);
        }
    } else {
        int idx = b * 256 + t;          // 0..8191
        int j  = idx & 7;
        int ln = (idx >> 3) & 63;
        int it = (idx >> 9) & 3;
        int ct = idx >> 11;
        int k  = it * 32 + (ln >> 4) * 8 + j;
        int ch = ct * 16 + (ln & 15);
        wfrag[idx] = (unsigned short)f2bf(W1s[k * C1 + ch]);
    }
}

// ---------------- fused: gemm1 (blocks 0..GB1) + edge partition (blocks GB1..GB1+PB) ----

__device__ __forceinline__ void gemm1_body(int blk, const float* __restrict__ x,
                                           const unsigned short* __restrict__ wfrag,
                                           const float* __restrict__ wad, const float* __restrict__ a_src,
                                           __half* __restrict__ hsh, float* __restrict__ as_out,
                                           float* __restrict__ ad_out) {
    int t = threadIdx.x;
    int lane = t & 63;
    int wv = t >> 6;
    int n0 = blk * 64 + wv * 16;
    int li = lane & 15, g = lane >> 4;

    int row = n0 + li;
    bool rv = row < NODES;
    const float* xr = x + (size_t)row * FIN + g * 8;

    f32x4 acc0 = {0.f,0.f,0.f,0.f}, acc1 = {0.f,0.f,0.f,0.f};
    f32x4 acc2 = {0.f,0.f,0.f,0.f}, acc3 = {0.f,0.f,0.f,0.f};
    bf16x8 af[4];
    float adp = 0.f;

    #pragma unroll
    for (int it = 0; it < 4; it++) {
        float xv[8];
        if (rv) {
            float4 lo = *reinterpret_cast<const float4*>(xr + it * 32);
            float4 hi = *reinterpret_cast<const float4*>(xr + it * 32 + 4);
            xv[0]=lo.x; xv[1]=lo.y; xv[2]=lo.z; xv[3]=lo.w;
            xv[4]=hi.x; xv[5]=hi.y; xv[6]=hi.z; xv[7]=hi.w;
        } else {
            #pragma unroll
            for (int j = 0; j < 8; j++) xv[j] = 0.f;
        }
        const float* wr = wad + g * 8 + it * 32;
        float4 wlo = *reinterpret_cast<const float4*>(wr);
        float4 whi = *reinterpret_cast<const float4*>(wr + 4);
        adp = fmaf(xv[0], wlo.x, adp); adp = fmaf(xv[1], wlo.y, adp);
        adp = fmaf(xv[2], wlo.z, adp); adp = fmaf(xv[3], wlo.w, adp);
        adp = fmaf(xv[4], whi.x, adp); adp = fmaf(xv[5], whi.y, adp);
        adp = fmaf(xv[6], whi.z, adp); adp = fmaf(xv[7], whi.w, adp);
        bf16x8 a;
        #pragma unroll
        for (int j = 0; j < 8; j++) a[j] = f2bf(xv[j]);
        af[it] = a;
    }

    const bf16x8* wfv = reinterpret_cast<const bf16x8*>(wfrag);
    #pragma unroll
    for (int it = 0; it < 4; it++) {
        acc0 = __builtin_amdgcn_mfma_f32_16x16x32_bf16(af[it], wfv[(0*4+it)*64 + lane], acc0, 0, 0, 0);
        acc1 = __builtin_amdgcn_mfma_f32_16x16x32_bf16(af[it], wfv[(1*4+it)*64 + lane], acc1, 0, 0, 0);
        acc2 = __builtin_amdgcn_mfma_f32_16x16x32_bf16(af[it], wfv[(2*4+it)*64 + lane], acc2, 0, 0, 0);
        acc3 = __builtin_amdgcn_mfma_f32_16x16x32_bf16(af[it], wfv[(3*4+it)*64 + lane], acc3, 0, 0, 0);
    }

    adp += __shfl_xor(adp, 16);
    adp += __shfl_xor(adp, 32);
    if (lane < 16 && rv) ad_out[row] = adp;

    float a0 = a_src[0 * 16 + li], a1 = a_src[1 * 16 + li];
    float a2 = a_src[2 * 16 + li], a3 = a_src[3 * 16 + li];
    float asp0 = acc0[0]*a0 + acc1[0]*a1 + acc2[0]*a2 + acc3[0]*a3;
    float asp1 = acc0[1]*a0 + acc1[1]*a1 + acc2[1]*a2 + acc3[1]*a3;
    float asp2 = acc0[2]*a0 + acc1[2]*a1 + acc2[2]*a2 + acc3[2]*a3;
    float asp3 = acc0[3]*a0 + acc1[3]*a1 + acc2[3]*a2 + acc3[3]*a3;
    #pragma unroll
    for (int o = 1; o <= 8; o <<= 1) {
        asp0 += __shfl_xor(asp0, o);
        asp1 += __shfl_xor(asp1, o);
        asp2 += __shfl_xor(asp2, o);
        asp3 += __shfl_xor(asp3, o);
    }
    if ((lane & 12) == 0) {
        int r = lane & 3;
        int n = n0 + 4 * g + r;
        if (n < NODES) {
            float av = (r == 0) ? asp0 : (r == 1) ? asp1 : (r == 2) ? asp2 : asp3;
            as_out[n] = av;
        }
    }

    #pragma unroll
    for (int r = 0; r < 4; r++) {
        int n = n0 + 4 * g + r;
        if (n < NODES) {
            __half* hb = hsh + (size_t)n * C1 + li;
            hb[ 0] = __float2half(acc0[r]);
            hb[16] = __float2half(acc1[r]);
            hb[32] = __float2half(acc2[r]);
            hb[48] = __float2half(acc3[r]);
        }
    }
}

__global__ __launch_bounds__(256) void k_fused1(const float* __restrict__ x,
                                                const unsigned short* __restrict__ wfrag,
                                                const float* __restrict__ wad, const float* __restrict__ a_src,
                                                __half* __restrict__ hsh, float* __restrict__ as_out,
                                                float* __restrict__ ad_out,
                                                const int* __restrict__ ei, int* bcur,
                                                unsigned* __restrict__ tmp) {
    __shared__ int hist[NBUCK], hbase[NBUCK];
    if (blockIdx.x < GB1) {
        gemm1_body(blockIdx.x, x, wfrag, wad, a_src, hsh, as_out, ad_out);
        return;
    }
    int t = threadIdx.x;
    for (int i = t; i < NBUCK; i += 256) hist[i] = 0;
    __syncthreads();
    const int* srcs = ei;
    const int* dsts = ei + NEDGE;
    int e_base = (blockIdx.x - GB1) * PTILE;
    unsigned pack[16];
    int bkt[16], slot[16];
    #pragma unroll
    for (int i = 0; i < 16; i++) {
        int e = e_base + i * 256 + t;
        bool valid = e < NEDGE;
        int s = valid ? srcs[e] : 0;
        int d = valid ? dsts[e] : 0;
        if ((unsigned)d >= NODES || (unsigned)s >= NODES) valid = false;
        bkt[i] = valid ? (d >> 7) : -1;
        pack[i] = (unsigned)s | ((unsigned)(d & (BK - 1)) << 17);
        slot[i] = valid ? atomicAdd(&hist[bkt[i]], 1) : -1;
    }
    __syncthreads();
    for (int i = t; i < NBUCK; i += 256)
        hbase[i] = hist[i] ? atomicAdd(&bcur[i], hist[i]) : 0;
    __syncthreads();
    #pragma unroll
    for (int i = 0; i < 16; i++) {
        if (slot[i] >= 0) {
            int pos = hbase[bkt[i]] + slot[i];
            if (pos < PCAP) tmp[(size_t)bkt[i] * PCAP + pos] = pack[i];
        }
    }
}

// P2: per bucket: own prefix-base -> counts -> local scan (offs) -> LDS scatter ->
// coalesced csr+pe write. p = exp(lrelu(as1[s]+ad1[d])) computed inline at writeout.
__global__ __launch_bounds__(256) void k_build(const unsigned* __restrict__ tmp, const int* __restrict__ bcur,
                                               const float* __restrict__ as1, const float* __restrict__ ad1,
                                               int* __restrict__ offs, int* __restrict__ csr,
                                               uint2* __restrict__ pe) {
    __shared__ int cnt[BK];
    __shared__ int ps_[BK];
    __shared__ int red[256];
    __shared__ int stage[PCAP + BK];
    int t = threadIdx.x;
    int b = blockIdx.x;
    int ecnt = bcur[b]; if (ecnt > PCAP) ecnt = PCAP;

    int part = 0;
    for (int i = t; i < b; i += 256) part += bcur[i];
    red[t] = part;
    __syncthreads();
    for (int o = 128; o; o >>= 1) {
        if (t < o) red[t] += red[t + o];
        __syncthreads();
    }
    int csrbase = red[0] + BK * b;
    const unsigned* ebuf = tmp + (size_t)b * PCAP;

    if (t < BK) cnt[t] = 0;
    __syncthreads();
    for (int e = t; e < ecnt; e += 256) {
        int dl = (ebuf[e] >> 17) & (BK - 1);
        atomicAdd(&cnt[dl], 1);
    }
    __syncthreads();
    int gn = b * BK + t;
    int own = 0;
    if (t < BK) {
        own = cnt[t] + ((gn < NODES) ? 1 : 0);
        ps_[t] = own;
    }
    __syncthreads();
    for (int o = 1; o < BK; o <<= 1) {
        int add = (t < BK && t >= o) ? ps_[t - o] : 0;
        __syncthreads();
        if (t < BK) ps_[t] += add;
        __syncthreads();
    }
    int total = ps_[BK - 1];
    if (t < BK && gn < NODES) {
        int excl = ps_[t] - own;
        stage[excl] = gn | (t << 17);
        cnt[t] = excl + 1;
        offs[gn] = csrbase + excl;
    }
    if (b == NBUCK - 1 && t == 0) offs[NODES] = ETOT;
    if (b == NBUCK - 1 && t < 16) pe[ETOT + t] = make_uint2(0u, 0u);
    __syncthreads();
    for (int e = t; e < ecnt; e += 256) {
        unsigned p = ebuf[e];
        int dl = (p >> 17) & (BK - 1);
        int slot = atomicAdd(&cnt[dl], 1);
        stage[slot] = (int)p;
    }
    __syncthreads();
    for (int j = t; j < total; j += 256) {
        int v = stage[j];
        int s = v & 0x1FFFF;
        int d = b * BK + (int)(((unsigned)v) >> 17);
        csr[csrbase + j] = s;
        float e = as1[s] + ad1[d];
        e = e > 0.f ? e : NEG * e;
        float p = __expf(fminf(e, 60.f));
        pe[csrbase + j] = make_uint2((unsigned)s, __float_as_uint(p));
    }
}

// ---------------- aggregation layer 1: pure gather, packed-fp16 accumulate ----------------

__global__ __launch_bounds__(256) void k_agg1(const int* __restrict__ offs, const uint2* __restrict__ pe,
                                              const __half* __restrict__ hsh, const float* __restrict__ b1,
                                              __half* __restrict__ h1h) {
    int w = threadIdx.x >> 6, lane = threadIdx.x & 63;
    int node = blockIdx.x * 4 + w;
    if (node >= NODES) return;
    int e0 = offs[node], e1 = offs[node + 1];
    int g = lane >> 4, l = lane & 15;
    __half2 acc01 = __floats2half2_rn(0.f, 0.f);
    __half2 acc23 = __floats2half2_rn(0.f, 0.f);
    float ssum = 0.f;
    for (int base = e0; base < e1; base += 16) {
        int ea = base + g, eb = ea + 4, ec = ea + 8, ed = ea + 12;
        uint2 spa = pe[ea];
        uint2 spb = pe[eb];
        uint2 spc = pe[ec];
        uint2 spd = pe[ed];
        float pa = ea < e1 ? __uint_as_float(spa.y) : 0.f;
        float pb = eb < e1 ? __uint_as_float(spb.y) : 0.f;
        float pc = ec < e1 ? __uint_as_float(spc.y) : 0.f;
        float pd = ed < e1 ? __uint_as_float(spd.y) : 0.f;
        uint2 ra = *reinterpret_cast<const uint2*>(hsh + (size_t)spa.x * C1 + l * 4);
        uint2 rb = *reinterpret_cast<const uint2*>(hsh + (size_t)spb.x * C1 + l * 4);
        uint2 rc = *reinterpret_cast<const uint2*>(hsh + (size_t)spc.x * C1 + l * 4);
        uint2 rd = *reinterpret_cast<const uint2*>(hsh + (size_t)spd.x * C1 + l * 4);
        ssum += (pa + pb) + (pc + pd);
        __half2 pha = __float2half2_rn(pa * PSCALE);
        __half2 phb = __float2half2_rn(pb * PSCALE);
        __half2 phc = __float2half2_rn(pc * PSCALE);
        __half2 phd = __float2half2_rn(pd * PSCALE);
        acc01 = __hfma2(pha, *reinterpret_cast<const __half2*>(&ra.x), acc01);
        acc23 = __hfma2(pha, *reinterpret_cast<const __half2*>(&ra.y), acc23);
        acc01 = __hfma2(phb, *reinterpret_cast<const __half2*>(&rb.x), acc01);
        acc23 = __hfma2(phb, *reinterpret_cast<const __half2*>(&rb.y), acc23);
        acc01 = __hfma2(phc, *reinterpret_cast<const __half2*>(&rc.x), acc01);
        acc23 = __hfma2(phc, *reinterpret_cast<const __half2*>(&rc.y), acc23);
        acc01 = __hfma2(phd, *reinterpret_cast<const __half2*>(&rd.x), acc01);
        acc23 = __hfma2(phd, *reinterpret_cast<const __half2*>(&rd.y), acc23);
    }
    ssum += __shfl_xor(ssum, 16); ssum += __shfl_xor(ssum, 32);
    unsigned u01 = *reinterpret_cast<unsigned*>(&acc01);
    unsigned u23 = *reinterpret_cast<unsigned*>(&acc23);
    unsigned v01 = (unsigned)__shfl_xor((int)u01, 16);
    unsigned v23 = (unsigned)__shfl_xor((int)u23, 16);
    acc01 = __hadd2(acc01, *reinterpret_cast<__half2*>(&v01));
    acc23 = __hadd2(acc23, *reinterpret_cast<__half2*>(&v23));
    u01 = *reinterpret_cast<unsigned*>(&acc01);
    u23 = *reinterpret_cast<unsigned*>(&acc23);
    v01 = (unsigned)__shfl_xor((int)u01, 32);
    v23 = (unsigned)__shfl_xor((int)u23, 32);
    acc01 = __hadd2(acc01, *reinterpret_cast<__half2*>(&v01));
    acc23 = __hadd2(acc23, *reinterpret_cast<__half2*>(&v23));
    if (g == 0) {
        float inv = 256.0f / (ssum + 1e-16f);
        float2 f01 = __half22float2(acc01);
        float2 f23 = __half22float2(acc23);
        float4 bv = reinterpret_cast<const float4*>(b1)[l];
        __half2 r01 = __floats2half2_rn(fmaf(f01.x, inv, bv.x), fmaf(f01.y, inv, bv.y));
        __half2 r23 = __floats2half2_rn(fmaf(f23.x, inv, bv.z), fmaf(f23.y, inv, bv.w));
        uint2 packed = make_uint2(*reinterpret_cast<unsigned*>(&r01), *reinterpret_cast<unsigned*>(&r23));
        reinterpret_cast<uint2*>(h1h + (size_t)node * C1)[l] = packed;
    }
}

// ---------------- BN stats: vectorized uint2 grid-stride, per-block partials ----------------
// h1h viewed as uint2[NODES*16]; stride BNBLK*256 is a multiple of 16, so each
// thread's channel-quad (idx%16) is fixed. ~12 independent 8B loads per thread.

__global__ __launch_bounds__(256) void k_bnstats(const __half* __restrict__ h1h, float* __restrict__ bnpart) {
    __shared__ float red[256][8];
    int t = threadIdx.x;
    const uint2* hv = reinterpret_cast<const uint2*>(h1h);
    const int total = NODES * 16;
    float s0=0.f,s1=0.f,s2=0.f,s3=0.f,q0=0.f,q1=0.f,q2=0.f,q3=0.f;
    for (int i = blockIdx.x * 256 + t; i < total; i += BNBLK * 256) {
        uint2 u = hv[i];
        float2 a = __half22float2(*reinterpret_cast<const __half2*>(&u.x));
        float2 b = __half22float2(*reinterpret_cast<const __half2*>(&u.y));
        s0 += a.x; q0 = fmaf(a.x, a.x, q0);
        s1 += a.y; q1 = fmaf(a.y, a.y, q1);
        s2 += b.x; q2 = fmaf(b.x, b.x, q2);
        s3 += b.y; q3 = fmaf(b.y, b.y, q3);
    }
    red[t][0]=s0; red[t][1]=s1; red[t][2]=s2; red[t][3]=s3;
    red[t][4]=q0; red[t][5]=q1; red[t][6]=q2; red[t][7]=q3;
    __syncthreads();
    if (t < 64) {
        int quad = t >> 2, j = t & 3;
        float ts = 0.f, tq = 0.f;
        #pragma unroll
        for (int k = 0; k < 16; k++) {
            ts += red[k * 16 + quad][j];
            tq += red[k * 16 + quad][j + 4];
        }
        bnpart[(size_t)blockIdx.x * 128 + t]      = ts;
        bnpart[(size_t)blockIdx.x * 128 + 64 + t] = tq;
    }
}

// ---------------- BN finalize (inline) + apply + ReLU + GEMM2 (+alpha dots) ----------------

__global__ __launch_bounds__(256) void k_bngemm2(const __half* __restrict__ h1h, const float* __restrict__ bnpart,
                                                 const float* __restrict__ gamma, const float* __restrict__ beta,
                                                 const float* __restrict__ W2s,
                                                 const float* __restrict__ wad2, const float* __restrict__ a2s,
                                                 float* __restrict__ hs2, float* __restrict__ as2,
                                                 float* __restrict__ ad2) {
    __shared__ float sc_s[64], sh_s[64];
    int t = threadIdx.x;
    if (t < 64) {
        float s = 0.f, q = 0.f;
        for (int b = 0; b < BNBLK; b++) {
            s += bnpart[(size_t)b * 128 + t];
            q += bnpart[(size_t)b * 128 + 64 + t];
        }
        float mu = s * (1.0f / NODES);
        float var = q * (1.0f / NODES) - mu * mu;
        if (var < 0.f) var = 0.f;
        float rinv = 1.0f / sqrtf(var + BNEPS);
        float sc = gamma[t] * rinv;
        sc_s[t] = sc;
        sh_s[t] = beta[t] - mu * sc;
    }
    __syncthreads();
    int n = blockIdx.x * 256 + t;
    if (n >= NODES) return;
    const uint2* hr = reinterpret_cast<const uint2*>(h1h + (size_t)n * C1);
    float h0 = 0.f, h1v = 0.f, adv = 0.f;
    #pragma unroll
    for (int c4 = 0; c4 < 16; c4++) {
        uint2 u = hr[c4];
        float2 v01 = __half22float2(*reinterpret_cast<const __half2*>(&u.x));
        float2 v23 = __half22float2(*reinterpret_cast<const __half2*>(&u.y));
        float vv[4] = {v01.x, v01.y, v23.x, v23.y};
        #pragma unroll
        for (int j = 0; j < 4; j++) {
            int c = c4 * 4 + j;
            float y = fmaf(vv[j], sc_s[c], sh_s[c]);
            y = fmaxf(y, 0.f);
            h0 = fmaf(y, W2s[c * 2 + 0], h0);
            h1v = fmaf(y, W2s[c * 2 + 1], h1v);
            adv = fmaf(y, wad2[c], adv);
        }
    }
    hs2[n * 2 + 0] = h0;
    hs2[n * 2 + 1] = h1v;
    as2[n] = fmaf(h0, a2s[0], h1v * a2s[1]);
    ad2[n] = adv;
}

// ---------------- aggregation layer 2: 16 lanes per node (mean degree ~17) ----------------

__global__ __launch_bounds__(256) void k_agg2(const int* __restrict__ offs, const int* __restrict__ csr,
                                              const float* __restrict__ as2, const float* __restrict__ ad2,
                                              const float* __restrict__ hs2, const float* __restrict__ b2,
                                              float* __restrict__ out) {
    int sub = threadIdx.x >> 4, l = threadIdx.x & 15;
    int node = blockIdx.x * 16 + sub;
    if (node >= NODES) return;
    int e0 = offs[node], e1 = offs[node + 1];
    float adn = ad2[node];
    float ssum = 0.f, A0 = 0.f, A1 = 0.f;
    const float2* h2 = reinterpret_cast<const float2*>(hs2);
    for (int e = e0 + l; e < e1; e += 16) {
        int s = csr[e];
        float v = as2[s] + adn;
        v = v > 0.f ? v : NEG * v;
        float p = __expf(fminf(v, 60.f));
        ssum += p;
        float2 hv = h2[s];
        A0 = fmaf(p, hv.x, A0);
        A1 = fmaf(p, hv.y, A1);
    }
    #pragma unroll
    for (int o = 1; o < 16; o <<= 1) {
        ssum += __shfl_xor(ssum, o);
        A0   += __shfl_xor(A0, o);
        A1   += __shfl_xor(A1, o);
    }
    if (l == 0) {
        float inv = 1.0f / (ssum + 1e-16f);
        float2 r = make_float2(fmaf(A0, inv, b2[0]), fmaf(A1, inv, b2[1]));
        reinterpret_cast<float2*>(out)[node] = r;
    }
}

// ---------------- host ----------------

static inline size_t align256(size_t x) { return (x + 255) & ~size_t(255); }

extern "C" void kernel_launch(void* const* d_in, const int* in_sizes, int n_in,
                              void* d_out, int out_size, void* d_ws, size_t ws_size,
                              hipStream_t stream) {
    const float* x     = (const float*)d_in[0];
    const int*   ei    = (const int*)d_in[1];
    const float* W1s   = (const float*)d_in[2];
    const float* W1d   = (const float*)d_in[3];
    const float* a1s   = (const float*)d_in[4];
    const float* a1d   = (const float*)d_in[5];
    const float* b1    = (const float*)d_in[6];
    const float* gamma = (const float*)d_in[7];
    const float* beta  = (const float*)d_in[8];
    const float* W2s   = (const float*)d_in[9];
    const float* W2d   = (const float*)d_in[10];
    const float* a2s   = (const float*)d_in[11];
    const float* a2d   = (const float*)d_in[12];
    const float* b2    = (const float*)d_in[13];
    float* out = (float*)d_out;

    char* w = (char*)d_ws;
    size_t off = 0;
    auto alloc = [&](size_t bytes) -> void* {
        void* p = w + off;
        off = align256(off + bytes);
        return p;
    };
    int* offs     = (int*)alloc((size_t)(NODES + 1) * 4);
    int* bcur     = (int*)alloc((size_t)NBUCK * 4);
    int* csr      = (int*)alloc((size_t)ETOT * 4);
    uint2* pe     = (uint2*)alloc((size_t)(ETOT + 16) * 8);
    __half* hs1h  = (__half*)alloc((size_t)NODES * C1 * 2);
    float* as1    = (float*)alloc((size_t)NODES * 4);
    float* ad1    = (float*)alloc((size_t)NODES * 4);
    __half* h1h   = (__half*)alloc((size_t)NODES * C1 * 2);
    float* csrtmp_own = (float*)alloc((size_t)NBUCK * PCAP * 4);
    float* hs2    = (float*)alloc((size_t)NODES * 2 * 4);
    float* as2    = (float*)alloc((size_t)NODES * 4);
    float* ad2    = (float*)alloc((size_t)NODES * 4);
    float* wad1   = (float*)alloc(FIN * 4);
    float* wad2   = (float*)alloc(C1 * 4);
    unsigned short* wfrag = (unsigned short*)alloc(8192 * 2);
    float* bnpart = (float*)alloc((size_t)BNBLK * 128 * 4);
    if (off > ws_size) return;

    unsigned* csr_tmp = (unsigned*)csrtmp_own;

    k_prep<<<34, 256, 0, stream>>>(W1s, W1d, a1d, W2d, a2d, wad1, wad2, wfrag, bcur);
    k_fused1<<<GB1 + PB, 256, 0, stream>>>(x, wfrag, wad1, a1s, hs1h, as1, ad1, ei, bcur, csr_tmp);
    k_build<<<NBUCK, 256, 0, stream>>>(csr_tmp, bcur, as1, ad1, offs, csr, pe);
    k_agg1<<<(NODES + 3) / 4, 256, 0, stream>>>(offs, pe, hs1h, b1, h1h);
    k_bnstats<<<BNBLK, 256, 0, stream>>>(h1h, bnpart);
    k_bngemm2<<<(NODES + 255) / 256, 256, 0, stream>>>(h1h, bnpart, gamma, beta, W2s, wad2, a2s, hs2, as2, ad2);
    k_agg2<<<(NODES + 15) / 16, 256, 0, stream>>>(offs, csr, as2, ad2, hs2, b2, out);
}

// Round 17
// 142.608 us; speedup vs baseline: 1.3060x; 1.0102x over previous
//
#include <hip/hip_runtime.h>
#include <hip/hip_fp16.h>
#include <math.h>

#define NODES 100000
#define NEDGE 1600000
#define ETOT  (NEDGE + NODES)
#define FIN   128
#define C1    64
#define NEG   0.2f
#define BNEPS 1e-5f
#define BNBLK 512
#define PSCALE 0.00390625f   // 2^-8 : fp16 accumulation scale in agg1

#define BK     128                         // nodes per bucket
#define NBUCK  ((NODES + BK - 1) / BK)     // 782
#define PCAP   2816                        // per-bucket edge cap (mean 2048, +17 sigma)
#define PTILE  4096                        // edges per k_part block
#define GB1    ((NODES + 63) / 64)         // gemm1 blocks: 1563
#define PB     ((NEDGE + PTILE - 1) / PTILE)  // part blocks: 391

typedef __attribute__((ext_vector_type(8))) short bf16x8;
typedef __attribute__((ext_vector_type(4))) float f32x4;

static __device__ __forceinline__ short f2bf(float f) {
    unsigned u = __builtin_bit_cast(unsigned, f);
    unsigned r = (u + 0x7FFFu + ((u >> 16) & 1u)) >> 16;
    return (short)r;
}

// ---------------- prep: wad vectors + W1s bf16 B-fragments + bcur zero ----------------

__global__ __launch_bounds__(256) void k_prep(const float* __restrict__ W1s,
                                              const float* __restrict__ W1d, const float* __restrict__ a1d,
                                              const float* __restrict__ W2d, const float* __restrict__ a2d,
                                              float* wad1, float* wad2, unsigned short* __restrict__ wfrag,
                                              int* __restrict__ bcur) {
    int t = threadIdx.x;
    int b = blockIdx.x;
    if (b == 33) {
        for (int i = t; i < NBUCK; i += 256) bcur[i] = 0;
    } else if (b == 32) {
        if (t < FIN) {
            float acc = 0.f;
            for (int c = 0; c < C1; c++) acc = fmaf(W1d[t * C1 + c], a1d[c], acc);
            wad1[t] = acc;
        }
        if (t < C1) {
            wad2[t] = fmaf(W2d[t * 2], a2d[0], W2d[t * 2 + 1] * a2d[1]);
        }
    } else {
        int idx = b * 256 + t;          // 0..8191
        int j  = idx & 7;
        int ln = (idx >> 3) & 63;
        int it = (idx >> 9) & 3;
        int ct = idx >> 11;
        int k  = it * 32 + (ln >> 4) * 8 + j;
        int ch = ct * 16 + (ln & 15);
        wfrag[idx] = (unsigned short)f2bf(W1s[k * C1 + ch]);
    }
}

// ---------------- fused: gemm1 (blocks 0..GB1) + edge partition (blocks GB1..GB1+PB) ----

__device__ __forceinline__ void gemm1_body(int blk, const float* __restrict__ x,
                                           const unsigned short* __restrict__ wfrag,
                                           const float* __restrict__ wad, const float* __restrict__ a_src,
                                           __half* __restrict__ hsh, float* __restrict__ as_out,
                                           float* __restrict__ ad_out) {
    int t = threadIdx.x;
    int lane = t & 63;
    int wv = t >> 6;
    int n0 = blk * 64 + wv * 16;
    int li = lane & 15, g = lane >> 4;

    int row = n0 + li;
    bool rv = row < NODES;
    const float* xr = x + (size_t)row * FIN + g * 8;

    f32x4 acc0 = {0.f,0.f,0.f,0.f}, acc1 = {0.f,0.f,0.f,0.f};
    f32x4 acc2 = {0.f,0.f,0.f,0.f}, acc3 = {0.f,0.f,0.f,0.f};
    bf16x8 af[4];
    float adp = 0.f;

    #pragma unroll
    for (int it = 0; it < 4; it++) {
        float xv[8];
        if (rv) {
            float4 lo = *reinterpret_cast<const float4*>(xr + it * 32);
            float4 hi = *reinterpret_cast<const float4*>(xr + it * 32 + 4);
            xv[0]=lo.x; xv[1]=lo.y; xv[2]=lo.z; xv[3]=lo.w;
            xv[4]=hi.x; xv[5]=hi.y; xv[6]=hi.z; xv[7]=hi.w;
        } else {
            #pragma unroll
            for (int j = 0; j < 8; j++) xv[j] = 0.f;
        }
        const float* wr = wad + g * 8 + it * 32;
        float4 wlo = *reinterpret_cast<const float4*>(wr);
        float4 whi = *reinterpret_cast<const float4*>(wr + 4);
        adp = fmaf(xv[0], wlo.x, adp); adp = fmaf(xv[1], wlo.y, adp);
        adp = fmaf(xv[2], wlo.z, adp); adp = fmaf(xv[3], wlo.w, adp);
        adp = fmaf(xv[4], whi.x, adp); adp = fmaf(xv[5], whi.y, adp);
        adp = fmaf(xv[6], whi.z, adp); adp = fmaf(xv[7], whi.w, adp);
        bf16x8 a;
        #pragma unroll
        for (int j = 0; j < 8; j++) a[j] = f2bf(xv[j]);
        af[it] = a;
    }

    const bf16x8* wfv = reinterpret_cast<const bf16x8*>(wfrag);
    #pragma unroll
    for (int it = 0; it < 4; it++) {
        acc0 = __builtin_amdgcn_mfma_f32_16x16x32_bf16(af[it], wfv[(0*4+it)*64 + lane], acc0, 0, 0, 0);
        acc1 = __builtin_amdgcn_mfma_f32_16x16x32_bf16(af[it], wfv[(1*4+it)*64 + lane], acc1, 0, 0, 0);
        acc2 = __builtin_amdgcn_mfma_f32_16x16x32_bf16(af[it], wfv[(2*4+it)*64 + lane], acc2, 0, 0, 0);
        acc3 = __builtin_amdgcn_mfma_f32_16x16x32_bf16(af[it], wfv[(3*4+it)*64 + lane], acc3, 0, 0, 0);
    }

    adp += __shfl_xor(adp, 16);
    adp += __shfl_xor(adp, 32);
    if (lane < 16 && rv) ad_out[row] = adp;

    float a0 = a_src[0 * 16 + li], a1 = a_src[1 * 16 + li];
    float a2 = a_src[2 * 16 + li], a3 = a_src[3 * 16 + li];
    float asp0 = acc0[0]*a0 + acc1[0]*a1 + acc2[0]*a2 + acc3[0]*a3;
    float asp1 = acc0[1]*a0 + acc1[1]*a1 + acc2[1]*a2 + acc3[1]*a3;
    float asp2 = acc0[2]*a0 + acc1[2]*a1 + acc2[2]*a2 + acc3[2]*a3;
    float asp3 = acc0[3]*a0 + acc1[3]*a1 + acc2[3]*a2 + acc3[3]*a3;
    #pragma unroll
    for (int o = 1; o <= 8; o <<= 1) {
        asp0 += __shfl_xor(asp0, o);
        asp1 += __shfl_xor(asp1, o);
        asp2 += __shfl_xor(asp2, o);
        asp3 += __shfl_xor(asp3, o);
    }
    if ((lane & 12) == 0) {
        int r = lane & 3;
        int n = n0 + 4 * g + r;
        if (n < NODES) {
            float av = (r == 0) ? asp0 : (r == 1) ? asp1 : (r == 2) ? asp2 : asp3;
            as_out[n] = av;
        }
    }

    #pragma unroll
    for (int r = 0; r < 4; r++) {
        int n = n0 + 4 * g + r;
        if (n < NODES) {
            __half* hb = hsh + (size_t)n * C1 + li;
            hb[ 0] = __float2half(acc0[r]);
            hb[16] = __float2half(acc1[r]);
            hb[32] = __float2half(acc2[r]);
            hb[48] = __float2half(acc3[r]);
        }
    }
}

__global__ __launch_bounds__(256) void k_fused1(const float* __restrict__ x,
                                                const unsigned short* __restrict__ wfrag,
                                                const float* __restrict__ wad, const float* __restrict__ a_src,
                                                __half* __restrict__ hsh, float* __restrict__ as_out,
                                                float* __restrict__ ad_out,
                                                const int* __restrict__ ei, int* bcur,
                                                unsigned* __restrict__ tmp) {
    __shared__ int hist[NBUCK], hbase[NBUCK];
    if (blockIdx.x < GB1) {
        gemm1_body(blockIdx.x, x, wfrag, wad, a_src, hsh, as_out, ad_out);
        return;
    }
    int t = threadIdx.x;
    for (int i = t; i < NBUCK; i += 256) hist[i] = 0;
    __syncthreads();
    const int* srcs = ei;
    const int* dsts = ei + NEDGE;
    int e_base = (blockIdx.x - GB1) * PTILE;
    unsigned pack[16];
    int bkt[16], slot[16];
    #pragma unroll
    for (int i = 0; i < 16; i++) {
        int e = e_base + i * 256 + t;
        bool valid = e < NEDGE;
        int s = valid ? srcs[e] : 0;
        int d = valid ? dsts[e] : 0;
        if ((unsigned)d >= NODES || (unsigned)s >= NODES) valid = false;
        bkt[i] = valid ? (d >> 7) : -1;
        pack[i] = (unsigned)s | ((unsigned)(d & (BK - 1)) << 17);
        slot[i] = valid ? atomicAdd(&hist[bkt[i]], 1) : -1;
    }
    __syncthreads();
    for (int i = t; i < NBUCK; i += 256)
        hbase[i] = hist[i] ? atomicAdd(&bcur[i], hist[i]) : 0;
    __syncthreads();
    #pragma unroll
    for (int i = 0; i < 16; i++) {
        if (slot[i] >= 0) {
            int pos = hbase[bkt[i]] + slot[i];
            if (pos < PCAP) tmp[(size_t)bkt[i] * PCAP + pos] = pack[i];
        }
    }
}

// P2: per bucket: own prefix-base -> counts -> local scan (offs) -> LDS scatter ->
// coalesced pe4 write. pe4 = s | (bf15(p) << 17); p = exp(lrelu(as1[s]+ad1[d])).
__global__ __launch_bounds__(256) void k_build(const unsigned* __restrict__ tmp, const int* __restrict__ bcur,
                                               const float* __restrict__ as1, const float* __restrict__ ad1,
                                               int* __restrict__ offs, unsigned* __restrict__ pe4) {
    __shared__ int cnt[BK];
    __shared__ int ps_[BK];
    __shared__ int red[256];
    __shared__ int stage[PCAP + BK];
    int t = threadIdx.x;
    int b = blockIdx.x;
    int ecnt = bcur[b]; if (ecnt > PCAP) ecnt = PCAP;

    int part = 0;
    for (int i = t; i < b; i += 256) part += bcur[i];
    red[t] = part;
    __syncthreads();
    for (int o = 128; o; o >>= 1) {
        if (t < o) red[t] += red[t + o];
        __syncthreads();
    }
    int csrbase = red[0] + BK * b;
    const unsigned* ebuf = tmp + (size_t)b * PCAP;

    if (t < BK) cnt[t] = 0;
    __syncthreads();
    for (int e = t; e < ecnt; e += 256) {
        int dl = (ebuf[e] >> 17) & (BK - 1);
        atomicAdd(&cnt[dl], 1);
    }
    __syncthreads();
    int gn = b * BK + t;
    int own = 0;
    if (t < BK) {
        own = cnt[t] + ((gn < NODES) ? 1 : 0);
        ps_[t] = own;
    }
    __syncthreads();
    for (int o = 1; o < BK; o <<= 1) {
        int add = (t < BK && t >= o) ? ps_[t - o] : 0;
        __syncthreads();
        if (t < BK) ps_[t] += add;
        __syncthreads();
    }
    int total = ps_[BK - 1];
    if (t < BK && gn < NODES) {
        int excl = ps_[t] - own;
        stage[excl] = gn | (t << 17);
        cnt[t] = excl + 1;
        offs[gn] = csrbase + excl;
    }
    if (b == NBUCK - 1 && t == 0) offs[NODES] = ETOT;
    if (b == NBUCK - 1 && t < 32) pe4[ETOT + t] = 0u;   // tail pad
    __syncthreads();
    for (int e = t; e < ecnt; e += 256) {
        unsigned p = ebuf[e];
        int dl = (p >> 17) & (BK - 1);
        int slot = atomicAdd(&cnt[dl], 1);
        stage[slot] = (int)p;
    }
    __syncthreads();
    for (int j = t; j < total; j += 256) {
        int v = stage[j];
        int s = v & 0x1FFFF;
        int d = b * BK + (int)(((unsigned)v) >> 17);
        float e = as1[s] + ad1[d];
        e = e > 0.f ? e : NEG * e;
        float p = __expf(fminf(e, 60.f));
        unsigned bf = ((unsigned)(unsigned short)f2bf(p)) & 0x7FFFu;  // p>=0: sign bit 0
        pe4[csrbase + j] = (unsigned)s | (bf << 17);
    }
}

// ---------------- aggregation layer 1: pure gather, packed-fp16 accumulate ----------------
// wave per node; 4 groups x 16 lanes. Per iteration each group loads ONE aligned uint4
// (4 edges packed s|bf15(p)) and issues 4 independent row gathers. Range-masked at
// both ends (base aligned down to 16); masked edges: p=0, s=0 (row 0 L1-hot).

__global__ __launch_bounds__(256) void k_agg1(const int* __restrict__ offs, const unsigned* __restrict__ pe4,
                                              const __half* __restrict__ hsh, const float* __restrict__ b1,
                                              __half* __restrict__ h1h) {
    int w = threadIdx.x >> 6, lane = threadIdx.x & 63;
    int node = blockIdx.x * 4 + w;
    if (node >= NODES) return;
    int e0 = offs[node], e1 = offs[node + 1];
    int g = lane >> 4, l = lane & 15;
    __half2 acc01 = __floats2half2_rn(0.f, 0.f);
    __half2 acc23 = __floats2half2_rn(0.f, 0.f);
    float ssum = 0.f;
    int base0 = e0 & ~15;
    for (int base = base0; base < e1; base += 16) {
        int eg = base + 4 * g;
        uint4 q = *reinterpret_cast<const uint4*>(pe4 + eg);
        unsigned wv[4] = {q.x, q.y, q.z, q.w};
        #pragma unroll
        for (int j = 0; j < 4; j++) {
            int e = eg + j;
            bool valid = (e >= e0) && (e < e1);
            unsigned ww = wv[j];
            float p = valid ? __uint_as_float((ww >> 17) << 16) : 0.f;
            int s = valid ? (int)(ww & 0x1FFFFu) : 0;
            uint2 r = *reinterpret_cast<const uint2*>(hsh + (size_t)s * C1 + l * 4);
            ssum += p;
            __half2 ph = __float2half2_rn(p * PSCALE);
            acc01 = __hfma2(ph, *reinterpret_cast<const __half2*>(&r.x), acc01);
            acc23 = __hfma2(ph, *reinterpret_cast<const __half2*>(&r.y), acc23);
        }
    }
    ssum += __shfl_xor(ssum, 16); ssum += __shfl_xor(ssum, 32);
    unsigned u01 = *reinterpret_cast<unsigned*>(&acc01);
    unsigned u23 = *reinterpret_cast<unsigned*>(&acc23);
    unsigned v01 = (unsigned)__shfl_xor((int)u01, 16);
    unsigned v23 = (unsigned)__shfl_xor((int)u23, 16);
    acc01 = __hadd2(acc01, *reinterpret_cast<__half2*>(&v01));
    acc23 = __hadd2(acc23, *reinterpret_cast<__half2*>(&v23));
    u01 = *reinterpret_cast<unsigned*>(&acc01);
    u23 = *reinterpret_cast<unsigned*>(&acc23);
    v01 = (unsigned)__shfl_xor((int)u01, 32);
    v23 = (unsigned)__shfl_xor((int)u23, 32);
    acc01 = __hadd2(acc01, *reinterpret_cast<__half2*>(&v01));
    acc23 = __hadd2(acc23, *reinterpret_cast<__half2*>(&v23));
    if (g == 0) {
        float inv = 256.0f / (ssum + 1e-16f);
        float2 f01 = __half22float2(acc01);
        float2 f23 = __half22float2(acc23);
        float4 bv = reinterpret_cast<const float4*>(b1)[l];
        __half2 r01 = __floats2half2_rn(fmaf(f01.x, inv, bv.x), fmaf(f01.y, inv, bv.y));
        __half2 r23 = __floats2half2_rn(fmaf(f23.x, inv, bv.z), fmaf(f23.y, inv, bv.w));
        uint2 packed = make_uint2(*reinterpret_cast<unsigned*>(&r01), *reinterpret_cast<unsigned*>(&r23));
        reinterpret_cast<uint2*>(h1h + (size_t)node * C1)[l] = packed;
    }
}

// ---------------- BN stats: vectorized uint2 grid-stride, per-block partials ----------------

__global__ __launch_bounds__(256) void k_bnstats(const __half* __restrict__ h1h, float* __restrict__ bnpart) {
    __shared__ float red[256][8];
    int t = threadIdx.x;
    const uint2* hv = reinterpret_cast<const uint2*>(h1h);
    const int total = NODES * 16;
    float s0=0.f,s1=0.f,s2=0.f,s3=0.f,q0=0.f,q1=0.f,q2=0.f,q3=0.f;
    for (int i = blockIdx.x * 256 + t; i < total; i += BNBLK * 256) {
        uint2 u = hv[i];
        float2 a = __half22float2(*reinterpret_cast<const __half2*>(&u.x));
        float2 b = __half22float2(*reinterpret_cast<const __half2*>(&u.y));
        s0 += a.x; q0 = fmaf(a.x, a.x, q0);
        s1 += a.y; q1 = fmaf(a.y, a.y, q1);
        s2 += b.x; q2 = fmaf(b.x, b.x, q2);
        s3 += b.y; q3 = fmaf(b.y, b.y, q3);
    }
    red[t][0]=s0; red[t][1]=s1; red[t][2]=s2; red[t][3]=s3;
    red[t][4]=q0; red[t][5]=q1; red[t][6]=q2; red[t][7]=q3;
    __syncthreads();
    if (t < 64) {
        int quad = t >> 2, j = t & 3;
        float ts = 0.f, tq = 0.f;
        #pragma unroll
        for (int k = 0; k < 16; k++) {
            ts += red[k * 16 + quad][j];
            tq += red[k * 16 + quad][j + 4];
        }
        bnpart[(size_t)blockIdx.x * 128 + t]      = ts;
        bnpart[(size_t)blockIdx.x * 128 + 64 + t] = tq;
    }
}

// ---------------- BN finalize (inline) + apply + ReLU + GEMM2 (+alpha dots) ----------------

__global__ __launch_bounds__(256) void k_bngemm2(const __half* __restrict__ h1h, const float* __restrict__ bnpart,
                                                 const float* __restrict__ gamma, const float* __restrict__ beta,
                                                 const float* __restrict__ W2s,
                                                 const float* __restrict__ wad2, const float* __restrict__ a2s,
                                                 float* __restrict__ hs2, float* __restrict__ as2,
                                                 float* __restrict__ ad2) {
    __shared__ float sc_s[64], sh_s[64];
    int t = threadIdx.x;
    if (t < 64) {
        float s = 0.f, q = 0.f;
        for (int b = 0; b < BNBLK; b++) {
            s += bnpart[(size_t)b * 128 + t];
            q += bnpart[(size_t)b * 128 + 64 + t];
        }
        float mu = s * (1.0f / NODES);
        float var = q * (1.0f / NODES) - mu * mu;
        if (var < 0.f) var = 0.f;
        float rinv = 1.0f / sqrtf(var + BNEPS);
        float sc = gamma[t] * rinv;
        sc_s[t] = sc;
        sh_s[t] = beta[t] - mu * sc;
    }
    __syncthreads();
    int n = blockIdx.x * 256 + t;
    if (n >= NODES) return;
    const uint2* hr = reinterpret_cast<const uint2*>(h1h + (size_t)n * C1);
    float h0 = 0.f, h1v = 0.f, adv = 0.f;
    #pragma unroll
    for (int c4 = 0; c4 < 16; c4++) {
        uint2 u = hr[c4];
        float2 v01 = __half22float2(*reinterpret_cast<const __half2*>(&u.x));
        float2 v23 = __half22float2(*reinterpret_cast<const __half2*>(&u.y));
        float vv[4] = {v01.x, v01.y, v23.x, v23.y};
        #pragma unroll
        for (int j = 0; j < 4; j++) {
            int c = c4 * 4 + j;
            float y = fmaf(vv[j], sc_s[c], sh_s[c]);
            y = fmaxf(y, 0.f);
            h0 = fmaf(y, W2s[c * 2 + 0], h0);
            h1v = fmaf(y, W2s[c * 2 + 1], h1v);
            adv = fmaf(y, wad2[c], adv);
        }
    }
    hs2[n * 2 + 0] = h0;
    hs2[n * 2 + 1] = h1v;
    as2[n] = fmaf(h0, a2s[0], h1v * a2s[1]);
    ad2[n] = adv;
}

// ---------------- aggregation layer 2: 16 lanes per node; src from pe4 ----------------

__global__ __launch_bounds__(256) void k_agg2(const int* __restrict__ offs, const unsigned* __restrict__ pe4,
                                              const float* __restrict__ as2, const float* __restrict__ ad2,
                                              const float* __restrict__ hs2, const float* __restrict__ b2,
                                              float* __restrict__ out) {
    int sub = threadIdx.x >> 4, l = threadIdx.x & 15;
    int node = blockIdx.x * 16 + sub;
    if (node >= NODES) return;
    int e0 = offs[node], e1 = offs[node + 1];
    float adn = ad2[node];
    float ssum = 0.f, A0 = 0.f, A1 = 0.f;
    const float2* h2 = reinterpret_cast<const float2*>(hs2);
    for (int e = e0 + l; e < e1; e += 16) {
        int s = (int)(pe4[e] & 0x1FFFFu);
        float v = as2[s] + adn;
        v = v > 0.f ? v : NEG * v;
        float p = __expf(fminf(v, 60.f));
        ssum += p;
        float2 hv = h2[s];
        A0 = fmaf(p, hv.x, A0);
        A1 = fmaf(p, hv.y, A1);
    }
    #pragma unroll
    for (int o = 1; o < 16; o <<= 1) {
        ssum += __shfl_xor(ssum, o);
        A0   += __shfl_xor(A0, o);
        A1   += __shfl_xor(A1, o);
    }
    if (l == 0) {
        float inv = 1.0f / (ssum + 1e-16f);
        float2 r = make_float2(fmaf(A0, inv, b2[0]), fmaf(A1, inv, b2[1]));
        reinterpret_cast<float2*>(out)[node] = r;
    }
}

// ---------------- host ----------------

static inline size_t align256(size_t x) { return (x + 255) & ~size_t(255); }

extern "C" void kernel_launch(void* const* d_in, const int* in_sizes, int n_in,
                              void* d_out, int out_size, void* d_ws, size_t ws_size,
                              hipStream_t stream) {
    const float* x     = (const float*)d_in[0];
    const int*   ei    = (const int*)d_in[1];
    const float* W1s   = (const float*)d_in[2];
    const float* W1d   = (const float*)d_in[3];
    const float* a1s   = (const float*)d_in[4];
    const float* a1d   = (const float*)d_in[5];
    const float* b1    = (const float*)d_in[6];
    const float* gamma = (const float*)d_in[7];
    const float* beta  = (const float*)d_in[8];
    const float* W2s   = (const float*)d_in[9];
    const float* W2d   = (const float*)d_in[10];
    const float* a2s   = (const float*)d_in[11];
    const float* a2d   = (const float*)d_in[12];
    const float* b2    = (const float*)d_in[13];
    float* out = (float*)d_out;

    char* w = (char*)d_ws;
    size_t off = 0;
    auto alloc = [&](size_t bytes) -> void* {
        void* p = w + off;
        off = align256(off + bytes);
        return p;
    };
    int* offs     = (int*)alloc((size_t)(NODES + 1) * 4);
    int* bcur     = (int*)alloc((size_t)NBUCK * 4);
    unsigned* pe4 = (unsigned*)alloc((size_t)(ETOT + 32) * 4);
    __half* hs1h  = (__half*)alloc((size_t)NODES * C1 * 2);
    float* as1    = (float*)alloc((size_t)NODES * 4);
    float* ad1    = (float*)alloc((size_t)NODES * 4);
    __half* h1h   = (__half*)alloc((size_t)NODES * C1 * 2);
    float* csrtmp_own = (float*)alloc((size_t)NBUCK * PCAP * 4);
    float* hs2    = (float*)alloc((size_t)NODES * 2 * 4);
    float* as2    = (float*)alloc((size_t)NODES * 4);
    float* ad2    = (float*)alloc((size_t)NODES * 4);
    float* wad1   = (float*)alloc(FIN * 4);
    float* wad2   = (float*)alloc(C1 * 4);
    unsigned short* wfrag = (unsigned short*)alloc(8192 * 2);
    float* bnpart = (float*)alloc((size_t)BNBLK * 128 * 4);
    if (off > ws_size) return;

    unsigned* csr_tmp = (unsigned*)csrtmp_own;

    k_prep<<<34, 256, 0, stream>>>(W1s, W1d, a1d, W2d, a2d, wad1, wad2, wfrag, bcur);
    k_fused1<<<GB1 + PB, 256, 0, stream>>>(x, wfrag, wad1, a1s, hs1h, as1, ad1, ei, bcur, csr_tmp);
    k_build<<<NBUCK, 256, 0, stream>>>(csr_tmp, bcur, as1, ad1, offs, pe4);
    k_agg1<<<(NODES + 3) / 4, 256, 0, stream>>>(offs, pe4, hs1h, b1, h1h);
    k_bnstats<<<BNBLK, 256, 0, stream>>>(h1h, bnpart);
    k_bngemm2<<<(NODES + 255) / 256, 256, 0, stream>>>(h1h, bnpart, gamma, beta, W2s, wad2, a2s, hs2, as2, ad2);
    k_agg2<<<(NODES + 15) / 16, 256, 0, stream>>>(offs, pe4, as2, ad2, hs2, b2, out);
}